// Round 1
// baseline (631.621 us; speedup 1.0000x reference)
//
#include <hip/hip_runtime.h>

#define CROP 48
#define NPIX (CROP * CROP)        // 2304
#define PADR 4                    // stencil halo radius (9x9 taps)
#define PW (CROP + 2 * PADR)      // 56
#define TPB 192                   // 16x12 tiles of 3x4 pixels
#define SINK_ITERS 50
#define TINYF 1e-8f

// conv over padded src with 9x9 weights; thread tile = rows r0..r0+2, cols c0..c0+3
__device__ __forceinline__ void conv9(const float* __restrict__ src,
                                      const float w[9][9],
                                      int r0, int c0, float acc[3][4]) {
#pragma unroll
    for (int i = 0; i < 3; ++i)
#pragma unroll
        for (int q = 0; q < 4; ++q) acc[i][q] = 0.0f;

#pragma unroll
    for (int iw = 0; iw < 11; ++iw) {
        // padded input row = r0 + iw (unpadded row r0-4+iw), cols c0 .. c0+11 (padded)
        const float4* rp = (const float4*)(src + (r0 + iw) * PW + c0);
        float4 f0 = rp[0], f1 = rp[1], f2 = rp[2];
        float win[12] = {f0.x, f0.y, f0.z, f0.w, f1.x, f1.y, f1.z, f1.w,
                         f2.x, f2.y, f2.z, f2.w};
#pragma unroll
        for (int i = 0; i < 3; ++i) {
            const int dy = iw - PADR - i;  // input_row - output_row
            if (dy < -PADR || dy > PADR) continue;
#pragma unroll
            for (int dx = 0; dx < 9; ++dx)
#pragma unroll
                for (int q = 0; q < 4; ++q)
                    acc[i][q] += w[dy + PADR][dx] * win[q + dx];
        }
    }
}

__global__ __launch_bounds__(TPB, 2)
void sinkhorn_kernel(const float* __restrict__ hm_gt,
                     const float* __restrict__ hm_pred,
                     const int* __restrict__ tops,
                     float* __restrict__ out) {
    __shared__ __align__(16) float sa[NPIX];
    __shared__ __align__(16) float sb[NPIX];
    __shared__ __align__(16) float su[PW * PW];
    __shared__ __align__(16) float sv[PW * PW];
    __shared__ float sred[8];

    const int t = threadIdx.x;
    const int blk = blockIdx.x;          // == crop row index ((bi*8+r)*5+c)
    const int bi = blk / 40;
    const int rr = (blk / 5) % 8;
    const int cc = blk % 5;
    const int y0 = tops[(bi * 8 + rr) * 2 + 0];
    const int x0 = tops[(bi * 8 + rr) * 2 + 1];

    const float* srcA = hm_gt + (size_t)(bi * 5 + cc) * 160 * 160;
    const float* srcB = hm_pred + (size_t)(bi * 5 + cc) * 160 * 160;

    // ---- load crops, compute sums ----
    float va[12], vb[12];
    float sumA = 0.0f, sumB = 0.0f;
#pragma unroll
    for (int k = 0; k < 12; ++k) {
        const int p = t + k * TPB;
        const int py = p / CROP, px = p % CROP;
        const float A = srcA[(y0 + py) * 160 + (x0 + px)];
        const float B = srcB[(y0 + py) * 160 + (x0 + px)];
        va[k] = A; vb[k] = B;
        sumA += A; sumB += B;
    }
#pragma unroll
    for (int o = 32; o > 0; o >>= 1) {
        sumA += __shfl_down(sumA, o, 64);
        sumB += __shfl_down(sumB, o, 64);
    }
    if ((t & 63) == 0) { sred[t >> 6] = sumA; sred[4 + (t >> 6)] = sumB; }
    __syncthreads();
    sumA = sred[0] + sred[1] + sred[2];
    sumB = sred[4] + sred[5] + sred[6];

    // ---- zero padded u/v ----
#pragma unroll
    for (int k = 0; k < 17; ++k) {
        const int p = t + k * TPB;
        if (p < PW * PW) { su[p] = 0.0f; sv[p] = 0.0f; }
    }
    __syncthreads();

    // ---- normalized marginals + u0 interior ----
    const float u0 = (float)(1.0 / 2304.0);
#pragma unroll
    for (int k = 0; k < 12; ++k) {
        const int p = t + k * TPB;
        const int py = p / CROP, px = p % CROP;
        sa[p] = va[k] / (sumA + TINYF);
        sb[p] = vb[k] / (sumB + TINYF);
        su[(py + PADR) * PW + (px + PADR)] = u0;
    }
    __syncthreads();

    // ---- Gibbs kernel weights (exact fp32 to match reference) ----
    float wreg[9][9];
#pragma unroll
    for (int dy = -4; dy <= 4; ++dy)
#pragma unroll
        for (int dx = -4; dx <= 4; ++dx) {
            const float d = sqrtf((float)(dy * dy + dx * dx));
            wreg[dy + 4][dx + 4] = expf(-d / 0.1f);
        }

    const int tr = t / 12, tc = t % 12;
    const int r0 = tr * 3, c0 = tc * 4;   // unpadded tile origin

    // ---- Sinkhorn iterations ----
#pragma unroll 1
    for (int it = 0; it < SINK_ITERS; ++it) {
        float acc[3][4];
        conv9(su, wreg, r0, c0, acc);       // (u @ K)
#pragma unroll
        for (int i = 0; i < 3; ++i) {
            const int gy = r0 + i;
            const float4 bb = *(const float4*)(sb + gy * CROP + c0);
            float4 res;
            res.x = bb.x / (acc[i][0] + TINYF);
            res.y = bb.y / (acc[i][1] + TINYF);
            res.z = bb.z / (acc[i][2] + TINYF);
            res.w = bb.w / (acc[i][3] + TINYF);
            *(float4*)(sv + (gy + PADR) * PW + c0 + PADR) = res;
        }
        __syncthreads();
        conv9(sv, wreg, r0, c0, acc);       // (v @ K^T) (K symmetric)
#pragma unroll
        for (int i = 0; i < 3; ++i) {
            const int gy = r0 + i;
            const float4 aa = *(const float4*)(sa + gy * CROP + c0);
            float4 res;
            res.x = aa.x / (acc[i][0] + TINYF);
            res.y = aa.y / (acc[i][1] + TINYF);
            res.z = aa.z / (acc[i][2] + TINYF);
            res.w = aa.w / (acc[i][3] + TINYF);
            *(float4*)(su + (gy + PADR) * PW + c0 + PADR) = res;
        }
        __syncthreads();
    }

    // ---- loss: sum_j convM(u)_j * v_j  (M = K .* dist, symmetric) ----
#pragma unroll
    for (int dy = -4; dy <= 4; ++dy)
#pragma unroll
        for (int dx = -4; dx <= 4; ++dx) {
            const float d = sqrtf((float)(dy * dy + dx * dx));
            wreg[dy + 4][dx + 4] = expf(-d / 0.1f) * d;
        }

    float accM[3][4];
    conv9(su, wreg, r0, c0, accM);
    float lsum = 0.0f;
#pragma unroll
    for (int i = 0; i < 3; ++i)
#pragma unroll
        for (int q = 0; q < 4; ++q)
            lsum += accM[i][q] * sv[(r0 + i + PADR) * PW + (c0 + q + PADR)];

#pragma unroll
    for (int o = 32; o > 0; o >>= 1) lsum += __shfl_down(lsum, o, 64);
    if ((t & 63) == 0) sred[t >> 6] = lsum;
    __syncthreads();
    if (t == 0) atomicAdd(out, sred[0] + sred[1] + sred[2]);
}

extern "C" void kernel_launch(void* const* d_in, const int* in_sizes, int n_in,
                              void* d_out, int out_size, void* d_ws, size_t ws_size,
                              hipStream_t stream) {
    (void)in_sizes; (void)n_in; (void)out_size; (void)d_ws; (void)ws_size;
    const float* hm_gt = (const float*)d_in[0];
    const float* hm_pred = (const float*)d_in[1];
    const int* tops = (const int*)d_in[2];
    float* out = (float*)d_out;

    hipMemsetAsync(out, 0, sizeof(float), stream);
    sinkhorn_kernel<<<dim3(640), dim3(TPB), 0, stream>>>(hm_gt, hm_pred, tops, out);
}

// Round 2
// 288.576 us; speedup vs baseline: 2.1888x; 2.1888x over previous
//
#include <hip/hip_runtime.h>

#define CROP 48
#define PADW 52                  // 48 + 2*2 halo; stride 52 spreads banks
#define TPB 192                  // 16x12 grid of 3x4-pixel tiles
#define SINK_ITERS 50
#define TINYF 1e-8f

__device__ __forceinline__ float uni(float x) {
    return __uint_as_float(__builtin_amdgcn_readfirstlane(__float_as_uint(x)));
}

// 5x5 conv over padded src; thread tile = unpadded rows r0..r0+2, cols c0..c0+3.
// Window = padded rows r0..r0+6, padded cols c0..c0+7 (both 16B-aligned).
__device__ __forceinline__ void conv5(const float* __restrict__ src,
                                      const float (*w)[5],
                                      int r0, int c0, float acc[3][4]) {
#pragma unroll
    for (int i = 0; i < 3; ++i)
#pragma unroll
        for (int q = 0; q < 4; ++q) acc[i][q] = 0.0f;

#pragma unroll
    for (int iw = 0; iw < 7; ++iw) {
        const float4* rp = (const float4*)(src + (r0 + iw) * PADW + c0);
        float4 f0 = rp[0], f1 = rp[1];
        float win[8] = {f0.x, f0.y, f0.z, f0.w, f1.x, f1.y, f1.z, f1.w};
#pragma unroll
        for (int i = 0; i < 3; ++i) {
            const int wy = iw - i;          // dy+2
            if (wy < 0 || wy > 4) continue;
#pragma unroll
            for (int wx = 0; wx < 5; ++wx)
#pragma unroll
                for (int q = 0; q < 4; ++q)
                    acc[i][q] += w[wy][wx] * win[q + wx];
        }
    }
}

__global__ __launch_bounds__(TPB)
void sinkhorn_kernel(const float* __restrict__ hm_gt,
                     const float* __restrict__ hm_pred,
                     const int* __restrict__ tops,
                     float* __restrict__ out) {
    __shared__ __align__(16) float su[PADW * PADW];
    __shared__ __align__(16) float sv[PADW * PADW];
    __shared__ float sred[8];

    const int t = threadIdx.x;
    const int blk = blockIdx.x;              // ((bi*8+rr)*5+cc)
    const int bi = blk / 40;
    const int rr = (blk / 5) % 8;
    const int cc = blk % 5;
    const int y0 = tops[(bi * 8 + rr) * 2 + 0];
    const int x0 = tops[(bi * 8 + rr) * 2 + 1];

    const float* srcA = hm_gt + (size_t)(bi * 5 + cc) * 25600;
    const float* srcB = hm_pred + (size_t)(bi * 5 + cc) * 25600;

    const int tr = t / 12, tc = t % 12;
    const int r0 = tr * 3, c0 = tc * 4;

    // ---- load own 3x4 tile of both crops into registers, accumulate sums ----
    float va[12], vb[12];
    float sumA = 0.0f, sumB = 0.0f;
#pragma unroll
    for (int i = 0; i < 3; ++i)
#pragma unroll
        for (int q = 0; q < 4; ++q) {
            const int gi = (y0 + r0 + i) * 160 + (x0 + c0 + q);
            const float A = srcA[gi];
            const float B = srcB[gi];
            va[i * 4 + q] = A; vb[i * 4 + q] = B;
            sumA += A; sumB += B;
        }
#pragma unroll
    for (int o = 32; o > 0; o >>= 1) {
        sumA += __shfl_down(sumA, o, 64);
        sumB += __shfl_down(sumB, o, 64);
    }
    if ((t & 63) == 0) { sred[t >> 6] = sumA; sred[4 + (t >> 6)] = sumB; }
    __syncthreads();
    sumA = sred[0] + sred[1] + sred[2];
    sumB = sred[4] + sred[5] + sred[6];
    const float rA = 1.0f / (sumA + TINYF);
    const float rB = 1.0f / (sumB + TINYF);
#pragma unroll
    for (int k = 0; k < 12; ++k) { va[k] *= rA; vb[k] *= rB; }

    // ---- zero padded u/v, then set u interior = 1/n ----
    __syncthreads();
#pragma unroll
    for (int k = 0; k < 15; ++k) {
        const int p = t + k * TPB;
        if (p < PADW * PADW) { su[p] = 0.0f; sv[p] = 0.0f; }
    }
    __syncthreads();
    const float u0 = 1.0f / 2304.0f;
#pragma unroll
    for (int i = 0; i < 3; ++i) {
        float2* wp = (float2*)(su + (r0 + i + 2) * PADW + c0 + 2);
        wp[0] = make_float2(u0, u0);
        wp[1] = make_float2(u0, u0);
    }
    __syncthreads();

    // ---- Gibbs kernel weights (wave-uniform -> SGPRs) ----
    float wK[5][5];
#pragma unroll
    for (int dy = -2; dy <= 2; ++dy)
#pragma unroll
        for (int dx = -2; dx <= 2; ++dx) {
            const float d = sqrtf((float)(dy * dy + dx * dx));
            wK[dy + 2][dx + 2] = uni(expf(-d / 0.1f));
        }

    float vv[12];

    // ---- Sinkhorn iterations ----
#pragma unroll 1
    for (int it = 0; it < SINK_ITERS; ++it) {
        float acc[3][4];
        conv5(su, wK, r0, c0, acc);              // (u @ K)
#pragma unroll
        for (int i = 0; i < 3; ++i) {
#pragma unroll
            for (int q = 0; q < 4; ++q)
                vv[i * 4 + q] = vb[i * 4 + q] *
                    __builtin_amdgcn_rcpf(acc[i][q] + TINYF);
            float2* wp = (float2*)(sv + (r0 + i + 2) * PADW + c0 + 2);
            wp[0] = make_float2(vv[i * 4 + 0], vv[i * 4 + 1]);
            wp[1] = make_float2(vv[i * 4 + 2], vv[i * 4 + 3]);
        }
        __syncthreads();
        conv5(sv, wK, r0, c0, acc);              // (v @ K^T), K symmetric
#pragma unroll
        for (int i = 0; i < 3; ++i) {
            float uu[4];
#pragma unroll
            for (int q = 0; q < 4; ++q)
                uu[q] = va[i * 4 + q] *
                    __builtin_amdgcn_rcpf(acc[i][q] + TINYF);
            float2* wp = (float2*)(su + (r0 + i + 2) * PADW + c0 + 2);
            wp[0] = make_float2(uu[0], uu[1]);
            wp[1] = make_float2(uu[2], uu[3]);
        }
        __syncthreads();
    }

    // ---- loss: (u @ M) . v with M = K .* dist (v is in registers) ----
    float wM[5][5];
#pragma unroll
    for (int dy = -2; dy <= 2; ++dy)
#pragma unroll
        for (int dx = -2; dx <= 2; ++dx) {
            const float d = sqrtf((float)(dy * dy + dx * dx));
            wM[dy + 2][dx + 2] = uni(expf(-d / 0.1f) * d);
        }
    float accM[3][4];
    conv5(su, wM, r0, c0, accM);
    float lsum = 0.0f;
#pragma unroll
    for (int i = 0; i < 3; ++i)
#pragma unroll
        for (int q = 0; q < 4; ++q)
            lsum += accM[i][q] * vv[i * 4 + q];

#pragma unroll
    for (int o = 32; o > 0; o >>= 1) lsum += __shfl_down(lsum, o, 64);
    if ((t & 63) == 0) sred[t >> 6] = lsum;
    __syncthreads();
    if (t == 0) atomicAdd(out, sred[0] + sred[1] + sred[2]);
}

extern "C" void kernel_launch(void* const* d_in, const int* in_sizes, int n_in,
                              void* d_out, int out_size, void* d_ws, size_t ws_size,
                              hipStream_t stream) {
    (void)in_sizes; (void)n_in; (void)out_size; (void)d_ws; (void)ws_size;
    const float* hm_gt = (const float*)d_in[0];
    const float* hm_pred = (const float*)d_in[1];
    const int* tops = (const int*)d_in[2];
    float* out = (float*)d_out;

    hipMemsetAsync(out, 0, sizeof(float), stream);
    sinkhorn_kernel<<<dim3(640), dim3(TPB), 0, stream>>>(hm_gt, hm_pred, tops, out);
}